// Round 1
// baseline (473.581 us; speedup 1.0000x reference)
//
#include <hip/hip_runtime.h>
#include <math.h>

#define BN 8192
#define DN 512
#define KN 8

// Zero the scalar accumulator (d_ws is re-poisoned to 0xAA before every call).
__global__ void zero_accum_kernel(float* a) { *a = 0.0f; }

// One block per row b: find the 8 lexicographically-smallest (|L[j]-L[b]|, j)
// pairs over j in [0, BN). Matches jax.lax.top_k(-res_abs, 8) tie semantics
// (equal values -> lower index first).
__global__ __launch_bounds__(256) void topk_kernel(const float* __restrict__ L,
                                                   int* __restrict__ idx_out) {
  __shared__ float sL[BN];        // 32 KB: all labels
  __shared__ float md[256 * KN];  // 8 KB: per-thread sorted dists
  __shared__ int   mi[256 * KN];  // 8 KB: per-thread sorted indices

  const int b = blockIdx.x;
  const int tid = threadIdx.x;

  for (int j = tid; j < BN; j += 256) sL[j] = L[j];
  __syncthreads();

  const float Li = sL[b];

  float d[KN];
  int   di[KN];
#pragma unroll
  for (int k = 0; k < KN; k++) { d[k] = 3.4e38f; di[k] = 0x7fffffff; }

  // Each thread scans 32 candidates, keeps its own sorted top-8.
  for (int j = tid; j < BN; j += 256) {
    float dist = fabsf(sL[j] - Li);
    if (dist < d[KN - 1] || (dist == d[KN - 1] && j < di[KN - 1])) {
      int p = KN - 1;
      while (p > 0 && (dist < d[p - 1] || (dist == d[p - 1] && j < di[p - 1]))) {
        d[p] = d[p - 1]; di[p] = di[p - 1]; --p;
      }
      d[p] = dist; di[p] = j;
    }
  }

#pragma unroll
  for (int k = 0; k < KN; k++) { md[tid * KN + k] = d[k]; mi[tid * KN + k] = di[k]; }

  // Tree merge: 256 sorted 8-lists -> 1 sorted 8-list (8 levels).
  for (int stride = 1; stride < 256; stride <<= 1) {
    __syncthreads();
    if ((tid & (2 * stride - 1)) == 0) {
      const int ai = tid * KN;
      const int bi = (tid + stride) * KN;
      float td[KN]; int ti[KN];
      int pa = 0, pb = 0;
#pragma unroll
      for (int k = 0; k < KN; k++) {   // pa+pb == k <= 7, so reads stay in-range
        float da = md[ai + pa], db = md[bi + pb];
        int   ia = mi[ai + pa], ib = mi[bi + pb];
        bool takeA = (da < db) || (da == db && ia < ib);
        td[k] = takeA ? da : db;
        ti[k] = takeA ? ia : ib;
        pa += takeA ? 1 : 0;
        pb += takeA ? 0 : 1;
      }
#pragma unroll
      for (int k = 0; k < KN; k++) { md[ai + k] = td[k]; mi[ai + k] = ti[k]; }
    }
  }

  if (tid == 0) {
#pragma unroll
    for (int k = 0; k < KN; k++) idx_out[b * KN + k] = mi[k];
  }
}

// One block per row: Gaussian-weighted neighbor mean + cosine similarity,
// atomicAdd the per-row sim into *accum.
__global__ __launch_bounds__(256) void wmean_cos_kernel(const float* __restrict__ S,
                                                        const float* __restrict__ L,
                                                        const int* __restrict__ idx,
                                                        float* __restrict__ accum) {
  const int b = blockIdx.x;
  const int tid = threadIdx.x;

  __shared__ int   sidx[KN];
  __shared__ float sw[KN];

  if (tid < KN) {
    int j = idx[b * KN + tid];
    sidx[tid] = j;
    float dd = L[j] - L[b];
    sw[tid] = expf(-dd * dd * (1.0f / 50.0f));  // 2*STD^2 = 50; norm const cancels
  }
  __syncthreads();
  if (tid == 0) {
    float s = 0.0f;
    for (int k = 0; k < KN; k++) s += sw[k];
    float inv = 1.0f / s;
    for (int k = 0; k < KN; k++) sw[k] *= inv;
  }
  __syncthreads();

  float w[KN]; int ix[KN];
#pragma unroll
  for (int k = 0; k < KN; k++) { w[k] = sw[k]; ix[k] = sidx[k]; }

  float dot = 0.0f, ns = 0.0f, nm = 0.0f;
  for (int dd = tid; dd < DN; dd += 256) {
    float s = S[b * DN + dd];
    float m = 0.0f;
#pragma unroll
    for (int k = 0; k < KN; k++) m += w[k] * S[ix[k] * DN + dd];
    dot += s * m;
    ns  += s * s;
    nm  += m * m;
  }

  // wave(64)-shuffle reduce, then cross-wave via LDS
#pragma unroll
  for (int off = 32; off > 0; off >>= 1) {
    dot += __shfl_down(dot, off, 64);
    ns  += __shfl_down(ns,  off, 64);
    nm  += __shfl_down(nm,  off, 64);
  }
  __shared__ float rdot[4], rns[4], rnm[4];
  const int wave = tid >> 6;
  if ((tid & 63) == 0) { rdot[wave] = dot; rns[wave] = ns; rnm[wave] = nm; }
  __syncthreads();
  if (tid == 0) {
    float td = 0.0f, tn = 0.0f, tm = 0.0f;
    for (int wv = 0; wv < 4; wv++) { td += rdot[wv]; tn += rns[wv]; tm += rnm[wv]; }
    float sim = td / ((1e-10f + sqrtf(tn)) * (1e-10f + sqrtf(tm)));
    atomicAdd(accum, sim);
  }
}

__global__ void finalize_kernel(const float* __restrict__ accum,
                                float* __restrict__ out) {
  out[0] = 1.0f - accum[0] * (1.0f / (float)BN);
}

extern "C" void kernel_launch(void* const* d_in, const int* in_sizes, int n_in,
                              void* d_out, int out_size, void* d_ws, size_t ws_size,
                              hipStream_t stream) {
  const float* S = (const float*)d_in[0];  // Struct (8192 x 512) fp32
  const float* L = (const float*)d_in[1];  // Label  (8192)       fp32
  float* out = (float*)d_out;              // scalar fp32

  int*   idx   = (int*)d_ws;                                   // 8192*8 ints = 256 KB
  float* accum = (float*)((char*)d_ws + BN * KN * sizeof(int)); // +4 B

  zero_accum_kernel<<<1, 1, 0, stream>>>(accum);
  topk_kernel<<<BN, 256, 0, stream>>>(L, idx);
  wmean_cos_kernel<<<BN, 256, 0, stream>>>(S, L, idx, accum);
  finalize_kernel<<<1, 1, 0, stream>>>(accum, out);
}

// Round 2
// 161.694 us; speedup vs baseline: 2.9289x; 2.9289x over previous
//
#include <hip/hip_runtime.h>
#include <math.h>

#define BN 8192
#define DN 512
#define KN 8
#define WIN 16          // window half-width around sorted position (>= KN, margin for ties)

typedef unsigned long long u64;
typedef unsigned int u32;

// ---- ws layout (bytes) ----
// keys      : u64  [8192]   @ 0        (65536)
// sortedIdx : int  [8192]   @ 65536    (32768)
// sortedLab : float[8192]   @ 98304    (32768)
// nidx      : int  [8192*8] @ 131072   (262144)
// wgt       : float[8192*8] @ 393216   (262144)
// partials  : float[2048]   @ 655360   (8192)
#define OFF_KEYS     0
#define OFF_SIDX     65536
#define OFF_SLAB     98304
#define OFF_NIDX     131072
#define OFF_WGT      393216
#define OFF_PART     655360

// Order-preserving float->uint transform (works for all floats).
__device__ __forceinline__ u32 flip_f32(u32 f) {
  return f ^ (u32)(((int)f >> 31) | 0x80000000);
}

// ---------------------------------------------------------------------------
// Kernel A: sort 8 chunks of 1024 keys each (bitonic stages k=2..1024 of the
// full 8192 network; direction bit uses the GLOBAL index).
// ---------------------------------------------------------------------------
__global__ __launch_bounds__(512) void sort_chunks_kernel(const float* __restrict__ L,
                                                          u64* __restrict__ keys) {
  __shared__ u64 sk[1024];
  const int tid = threadIdx.x;
  const int base = blockIdx.x * 1024;

  for (int i = tid; i < 1024; i += 512) {
    int g = base + i;
    u32 bits = __float_as_uint(L[g]);
    sk[i] = ((u64)flip_f32(bits) << 32) | (u32)g;
  }
  __syncthreads();

  for (int k = 2; k <= 1024; k <<= 1) {
    for (int j = k >> 1; j > 0; j >>= 1) {
      for (int i = tid; i < 1024; i += 512) {
        int ixj = i ^ j;
        if (ixj > i) {
          bool up = (((base + i) & k) == 0);
          u64 a = sk[i], b = sk[ixj];
          if ((a > b) == up) { sk[i] = b; sk[ixj] = a; }
        }
      }
      __syncthreads();
    }
  }

  for (int i = tid; i < 1024; i += 512) keys[base + i] = sk[i];
}

// ---------------------------------------------------------------------------
// Kernel B: single-block bitonic merge stages k=2048..8192, then emit
// sortedIdx[p], sortedLab[p].
// ---------------------------------------------------------------------------
__global__ __launch_bounds__(1024) void merge_sorted_kernel(const float* __restrict__ L,
                                                            u64* __restrict__ keys,
                                                            int* __restrict__ sortedIdx,
                                                            float* __restrict__ sortedLab) {
  __shared__ u64 sk[BN];   // 64 KB
  const int tid = threadIdx.x;

  for (int i = tid; i < BN; i += 1024) sk[i] = keys[i];
  __syncthreads();

  for (int k = 2048; k <= BN; k <<= 1) {
    for (int j = k >> 1; j > 0; j >>= 1) {
      for (int i = tid; i < BN; i += 1024) {
        int ixj = i ^ j;
        if (ixj > i) {
          bool up = ((i & k) == 0);
          u64 a = sk[i], b = sk[ixj];
          if ((a > b) == up) { sk[i] = b; sk[ixj] = a; }
        }
      }
      __syncthreads();
    }
  }

  for (int i = tid; i < BN; i += 1024) {
    int idx = (int)(u32)sk[i];
    sortedIdx[i] = idx;
    sortedLab[i] = L[idx];
  }
}

// ---------------------------------------------------------------------------
// Kernel C: per sorted position p, exact lexicographic top-8 of (dist, idx)
// over the +-WIN window; emit neighbor indices + normalized Gaussian weights.
// ---------------------------------------------------------------------------
__global__ __launch_bounds__(256) void select_topk_kernel(const int* __restrict__ sortedIdx,
                                                          const float* __restrict__ sortedLab,
                                                          int* __restrict__ nidx,
                                                          float* __restrict__ wgt) {
  __shared__ float lab[256 + 2 * WIN];
  __shared__ int   sid[256 + 2 * WIN];

  const int tid = threadIdx.x;
  const int base = blockIdx.x * 256;
  const int p = base + tid;

  for (int s = tid; s < 256 + 2 * WIN; s += 256) {
    int g = base - WIN + s;
    int gc = min(max(g, 0), BN - 1);
    lab[s] = sortedLab[gc];
    sid[s] = sortedIdx[gc];
  }
  __syncthreads();

  const float Lb = lab[tid + WIN];
  const int   b  = sid[tid + WIN];

  float d[KN]; int di[KN];
#pragma unroll
  for (int k = 0; k < KN; k++) { d[k] = 3.4e38f; di[k] = 0x7fffffff; }

  for (int o = -WIN; o <= WIN; ++o) {
    int q = p + o;
    if (q < 0 || q >= BN) continue;
    int s = tid + WIN + o;
    float cd = fabsf(lab[s] - Lb);
    int   cj = sid[s];
    // branchless bubble insertion, lexicographic (dist, idx)
#pragma unroll
    for (int k = 0; k < KN; k++) {
      bool less = (cd < d[k]) || (cd == d[k] && cj < di[k]);
      float od = d[k]; int oj = di[k];
      d[k]  = less ? cd : od;  di[k] = less ? cj : oj;
      cd    = less ? od : cd;  cj    = less ? oj : cj;
    }
  }

  float w[KN];
  float ssum = 0.0f;
#pragma unroll
  for (int k = 0; k < KN; k++) {
    w[k] = expf(-d[k] * d[k] * (1.0f / 50.0f));  // 2*STD^2 = 50; const factor cancels
    ssum += w[k];
  }
  float inv = 1.0f / ssum;
#pragma unroll
  for (int k = 0; k < KN; k++) {
    nidx[b * KN + k] = di[k];
    wgt[b * KN + k]  = w[k] * inv;
  }
}

// ---------------------------------------------------------------------------
// Kernel D: one wave (64 lanes) per row. Gather 8 neighbor rows, weighted
// mean, cosine sim. One partial per block (4 rows) -> partials[blockIdx].
// ---------------------------------------------------------------------------
__global__ __launch_bounds__(256) void wmean_cos_kernel(const float* __restrict__ S,
                                                        const int* __restrict__ nidx,
                                                        const float* __restrict__ wgt,
                                                        float* __restrict__ partials) {
  const int tid  = threadIdx.x;
  const int lane = tid & 63;
  const int wv   = tid >> 6;
  const int b    = blockIdx.x * 4 + wv;

  int ix[KN]; float w[KN];
#pragma unroll
  for (int k = 0; k < KN; k++) { ix[k] = nidx[b * KN + k]; w[k] = wgt[b * KN + k]; }

  const float4* Srow = (const float4*)(S + (size_t)b * DN);
  float4 s0 = Srow[lane];
  float4 s1 = Srow[lane + 64];

  float4 m0 = make_float4(0.f, 0.f, 0.f, 0.f);
  float4 m1 = make_float4(0.f, 0.f, 0.f, 0.f);
#pragma unroll
  for (int k = 0; k < KN; k++) {
    const float4* Nrow = (const float4*)(S + (size_t)ix[k] * DN);
    float4 n0 = Nrow[lane];
    float4 n1 = Nrow[lane + 64];
    float wk = w[k];
    m0.x = fmaf(wk, n0.x, m0.x); m0.y = fmaf(wk, n0.y, m0.y);
    m0.z = fmaf(wk, n0.z, m0.z); m0.w = fmaf(wk, n0.w, m0.w);
    m1.x = fmaf(wk, n1.x, m1.x); m1.y = fmaf(wk, n1.y, m1.y);
    m1.z = fmaf(wk, n1.z, m1.z); m1.w = fmaf(wk, n1.w, m1.w);
  }

  float dot = s0.x * m0.x + s0.y * m0.y + s0.z * m0.z + s0.w * m0.w
            + s1.x * m1.x + s1.y * m1.y + s1.z * m1.z + s1.w * m1.w;
  float ns  = s0.x * s0.x + s0.y * s0.y + s0.z * s0.z + s0.w * s0.w
            + s1.x * s1.x + s1.y * s1.y + s1.z * s1.z + s1.w * s1.w;
  float nm  = m0.x * m0.x + m0.y * m0.y + m0.z * m0.z + m0.w * m0.w
            + m1.x * m1.x + m1.y * m1.y + m1.z * m1.z + m1.w * m1.w;

#pragma unroll
  for (int off = 32; off > 0; off >>= 1) {
    dot += __shfl_down(dot, off, 64);
    ns  += __shfl_down(ns,  off, 64);
    nm  += __shfl_down(nm,  off, 64);
  }

  __shared__ float psim[4];
  if (lane == 0) {
    psim[wv] = dot / ((1e-10f + sqrtf(ns)) * (1e-10f + sqrtf(nm)));
  }
  __syncthreads();
  if (tid == 0) {
    partials[blockIdx.x] = psim[0] + psim[1] + psim[2] + psim[3];
  }
}

// ---------------------------------------------------------------------------
// Kernel E: reduce 2048 partials -> out[0] = 1 - sum/8192.
// ---------------------------------------------------------------------------
__global__ __launch_bounds__(256) void finalize_kernel(const float* __restrict__ partials,
                                                       float* __restrict__ out) {
  const int tid = threadIdx.x;
  float s = 0.0f;
  for (int i = tid; i < 2048; i += 256) s += partials[i];
#pragma unroll
  for (int off = 32; off > 0; off >>= 1) s += __shfl_down(s, off, 64);
  __shared__ float ps[4];
  if ((tid & 63) == 0) ps[tid >> 6] = s;
  __syncthreads();
  if (tid == 0) {
    float tot = ps[0] + ps[1] + ps[2] + ps[3];
    out[0] = 1.0f - tot * (1.0f / (float)BN);
  }
}

extern "C" void kernel_launch(void* const* d_in, const int* in_sizes, int n_in,
                              void* d_out, int out_size, void* d_ws, size_t ws_size,
                              hipStream_t stream) {
  const float* S = (const float*)d_in[0];  // Struct (8192 x 512) fp32
  const float* L = (const float*)d_in[1];  // Label  (8192)       fp32
  float* out = (float*)d_out;

  char* ws = (char*)d_ws;
  u64*   keys      = (u64*)  (ws + OFF_KEYS);
  int*   sortedIdx = (int*)  (ws + OFF_SIDX);
  float* sortedLab = (float*)(ws + OFF_SLAB);
  int*   nidx      = (int*)  (ws + OFF_NIDX);
  float* wgt       = (float*)(ws + OFF_WGT);
  float* partials  = (float*)(ws + OFF_PART);

  sort_chunks_kernel <<<8,    512,  0, stream>>>(L, keys);
  merge_sorted_kernel<<<1,    1024, 0, stream>>>(L, keys, sortedIdx, sortedLab);
  select_topk_kernel <<<32,   256,  0, stream>>>(sortedIdx, sortedLab, nidx, wgt);
  wmean_cos_kernel   <<<2048, 256,  0, stream>>>(S, nidx, wgt, partials);
  finalize_kernel    <<<1,    256,  0, stream>>>(partials, out);
}

// Round 3
// 120.598 us; speedup vs baseline: 3.9269x; 1.3408x over previous
//
#include <hip/hip_runtime.h>
#include <math.h>

#define BN 8192
#define DN 512
#define KN 8
#define WIN 16          // window half-width around sorted position (>= KN, margin for ties)

typedef unsigned long long u64;
typedef unsigned int u32;

// ---- ws layout (bytes) ----  total 598016 B (< known-good 663K)
// sortedIdx : int  [8192]    @ 0
// sortedLab : float[8192]    @ 32768
// keys0     : u64  [8192]    @ 65536    (dead after pass 3)
// keys1     : u64  [8192]    @ 131072   (dead after pass 2)
// nidx      : int  [8192*8]  @ 65536    (overlays keys; written after sort done)
// wgt       : float[8192*8]  @ 327680
// partials  : float[2048]    @ 589824
#define OFF_SIDX  0
#define OFF_SLAB  32768
#define OFF_K0    65536
#define OFF_K1    131072
#define OFF_NIDX  65536
#define OFF_WGT   327680
#define OFF_PART  589824

// Order-preserving float->uint transform.
__device__ __forceinline__ u32 flip_f32(u32 f) {
  return f ^ (u32)(((int)f >> 31) | 0x80000000);
}

// ---------------------------------------------------------------------------
// Kernel A: bitonic-sort 8 chunks of 1024 keys, each fully ASCENDING
// (local direction bits), feeding the merge-path passes.
// ---------------------------------------------------------------------------
__global__ __launch_bounds__(512) void sort_chunks_kernel(const float* __restrict__ L,
                                                          u64* __restrict__ keys) {
  __shared__ u64 sk[1024];
  const int tid = threadIdx.x;
  const int base = blockIdx.x * 1024;

  for (int i = tid; i < 1024; i += 512) {
    int g = base + i;
    u32 bits = __float_as_uint(L[g]);
    sk[i] = ((u64)flip_f32(bits) << 32) | (u32)g;
  }
  __syncthreads();

  for (int k = 2; k <= 1024; k <<= 1) {
    for (int j = k >> 1; j > 0; j >>= 1) {
      for (int i = tid; i < 1024; i += 512) {
        int ixj = i ^ j;
        if (ixj > i) {
          bool up = ((i & k) == 0);   // local bits -> chunk ends fully ascending
          u64 a = sk[i], b = sk[ixj];
          if ((a > b) == up) { sk[i] = b; sk[ixj] = a; }
        }
      }
      __syncthreads();
    }
  }

  for (int i = tid; i < 1024; i += 512) keys[base + i] = sk[i];
}

// ---------------------------------------------------------------------------
// Kernel B: merge-path pass. Merges adjacent sorted runs of length RUN into
// runs of 2*RUN. One thread per output element; co-rank via binary search.
// Keys are unique (index in low bits) so the merge is exact/stable.
// FINAL pass emits sortedIdx / sortedLab directly (unflips the float).
// ---------------------------------------------------------------------------
template <int RUN, bool FINAL>
__global__ __launch_bounds__(256) void merge_pass_kernel(const u64* __restrict__ in,
                                                         u64* __restrict__ outk,
                                                         int* __restrict__ sIdx,
                                                         float* __restrict__ sLab) {
  const int t = blockIdx.x * 256 + threadIdx.x;   // 0..8191
  const int seg = t / (2 * RUN);
  const int o   = t & (2 * RUN - 1);
  const u64* A = in + seg * 2 * RUN;
  const u64* B = A + RUN;

  int lo = (o > RUN) ? (o - RUN) : 0;
  int hi = (o < RUN) ? o : RUN;
  while (lo < hi) {
    int a = (lo + hi) >> 1;          // a < hi <= RUN, and o-a >= 1 (A[a], B[o-a-1] valid)
    if (A[a] < B[o - a - 1]) lo = a + 1; else hi = a;
  }
  const int a = lo, b = o - a;
  u64 va = (a < RUN) ? A[a] : 0xFFFFFFFFFFFFFFFFull;
  u64 vb = (b < RUN) ? B[b] : 0xFFFFFFFFFFFFFFFFull;
  u64 v = (va < vb) ? va : vb;

  if (FINAL) {
    u32 f = (u32)(v >> 32);
    u32 orig = (f & 0x80000000u) ? (f ^ 0x80000000u) : ~f;  // unflip
    sIdx[t] = (int)(u32)v;
    sLab[t] = __uint_as_float(orig);
  } else {
    outk[t] = v;
  }
}

// ---------------------------------------------------------------------------
// Kernel C: per sorted position p, exact lexicographic top-8 of (dist, idx)
// over the +-WIN window; emit neighbor indices + normalized Gaussian weights,
// indexed by SORTED position (coalesced for the gather kernel).
// ---------------------------------------------------------------------------
__global__ __launch_bounds__(256) void select_topk_kernel(const int* __restrict__ sortedIdx,
                                                          const float* __restrict__ sortedLab,
                                                          int* __restrict__ nidx,
                                                          float* __restrict__ wgt) {
  __shared__ float lab[256 + 2 * WIN];
  __shared__ int   sid[256 + 2 * WIN];

  const int tid = threadIdx.x;
  const int base = blockIdx.x * 256;
  const int p = base + tid;

  for (int s = tid; s < 256 + 2 * WIN; s += 256) {
    int g = base - WIN + s;
    int gc = min(max(g, 0), BN - 1);
    lab[s] = sortedLab[gc];
    sid[s] = sortedIdx[gc];
  }
  __syncthreads();

  const float Lb = lab[tid + WIN];

  float d[KN]; int di[KN];
#pragma unroll
  for (int k = 0; k < KN; k++) { d[k] = 3.4e38f; di[k] = 0x7fffffff; }

  for (int o = -WIN; o <= WIN; ++o) {
    int q = p + o;
    if (q < 0 || q >= BN) continue;   // clamped LDS entries never consumed
    int s = tid + WIN + o;
    float cd = fabsf(lab[s] - Lb);
    int   cj = sid[s];
#pragma unroll
    for (int k = 0; k < KN; k++) {    // branchless lexicographic bubble insert
      bool less = (cd < d[k]) || (cd == d[k] && cj < di[k]);
      float od = d[k]; int oj = di[k];
      d[k]  = less ? cd : od;  di[k] = less ? cj : oj;
      cd    = less ? od : cd;  cj    = less ? oj : cj;
    }
  }

  float w[KN];
  float ssum = 0.0f;
#pragma unroll
  for (int k = 0; k < KN; k++) {
    w[k] = expf(-d[k] * d[k] * (1.0f / 50.0f));  // 2*STD^2 = 50; const cancels
    ssum += w[k];
  }
  float inv = 1.0f / ssum;
#pragma unroll
  for (int k = 0; k < KN; k++) {
    nidx[p * KN + k] = di[k];
    wgt[p * KN + k]  = w[k] * inv;
  }
}

// ---------------------------------------------------------------------------
// Kernel D: one wave per row, rows visited in SORTED-label order with an XCD
// swizzle: adjacent sorted rows share ~7/8 neighbors, and each XCD's 1024-row
// range touches ~2 MB of Struct -> per-XCD L2 resident.
// ---------------------------------------------------------------------------
__global__ __launch_bounds__(256) void wmean_cos_kernel(const float* __restrict__ S,
                                                        const int* __restrict__ sortedIdx,
                                                        const int* __restrict__ nidx,
                                                        const float* __restrict__ wgt,
                                                        float* __restrict__ partials) {
  const int tid  = threadIdx.x;
  const int lane = tid & 63;
  const int wv   = tid >> 6;
  const int blk  = blockIdx.x;                       // 0..2047
  const int swz  = ((blk & 7) << 8) | (blk >> 3);    // XCD x -> sorted range [x*1024,(x+1)*1024)
  const int p    = swz * 4 + wv;                     // sorted position
  const int b    = sortedIdx[p];                     // original row

  int ix[KN]; float w[KN];
#pragma unroll
  for (int k = 0; k < KN; k++) { ix[k] = nidx[p * KN + k]; w[k] = wgt[p * KN + k]; }

  const float4* Srow = (const float4*)(S + (size_t)b * DN);
  float4 s0 = Srow[lane];
  float4 s1 = Srow[lane + 64];

  float4 m0 = make_float4(0.f, 0.f, 0.f, 0.f);
  float4 m1 = make_float4(0.f, 0.f, 0.f, 0.f);
#pragma unroll
  for (int k = 0; k < KN; k++) {
    const float4* Nrow = (const float4*)(S + (size_t)ix[k] * DN);
    float4 n0 = Nrow[lane];
    float4 n1 = Nrow[lane + 64];
    float wk = w[k];
    m0.x = fmaf(wk, n0.x, m0.x); m0.y = fmaf(wk, n0.y, m0.y);
    m0.z = fmaf(wk, n0.z, m0.z); m0.w = fmaf(wk, n0.w, m0.w);
    m1.x = fmaf(wk, n1.x, m1.x); m1.y = fmaf(wk, n1.y, m1.y);
    m1.z = fmaf(wk, n1.z, m1.z); m1.w = fmaf(wk, n1.w, m1.w);
  }

  float dot = s0.x * m0.x + s0.y * m0.y + s0.z * m0.z + s0.w * m0.w
            + s1.x * m1.x + s1.y * m1.y + s1.z * m1.z + s1.w * m1.w;
  float ns  = s0.x * s0.x + s0.y * s0.y + s0.z * s0.z + s0.w * s0.w
            + s1.x * s1.x + s1.y * s1.y + s1.z * s1.z + s1.w * s1.w;
  float nm  = m0.x * m0.x + m0.y * m0.y + m0.z * m0.z + m0.w * m0.w
            + m1.x * m1.x + m1.y * m1.y + m1.z * m1.z + m1.w * m1.w;

#pragma unroll
  for (int off = 32; off > 0; off >>= 1) {
    dot += __shfl_down(dot, off, 64);
    ns  += __shfl_down(ns,  off, 64);
    nm  += __shfl_down(nm,  off, 64);
  }

  __shared__ float psim[4];
  if (lane == 0) {
    psim[wv] = dot / ((1e-10f + sqrtf(ns)) * (1e-10f + sqrtf(nm)));
  }
  __syncthreads();
  if (tid == 0) {
    partials[blk] = psim[0] + psim[1] + psim[2] + psim[3];
  }
}

// ---------------------------------------------------------------------------
// Kernel E: reduce 2048 partials -> out[0] = 1 - sum/8192.
// ---------------------------------------------------------------------------
__global__ __launch_bounds__(256) void finalize_kernel(const float* __restrict__ partials,
                                                       float* __restrict__ out) {
  const int tid = threadIdx.x;
  float s = 0.0f;
  for (int i = tid; i < 2048; i += 256) s += partials[i];
#pragma unroll
  for (int off = 32; off > 0; off >>= 1) s += __shfl_down(s, off, 64);
  __shared__ float ps[4];
  if ((tid & 63) == 0) ps[tid >> 6] = s;
  __syncthreads();
  if (tid == 0) {
    float tot = ps[0] + ps[1] + ps[2] + ps[3];
    out[0] = 1.0f - tot * (1.0f / (float)BN);
  }
}

extern "C" void kernel_launch(void* const* d_in, const int* in_sizes, int n_in,
                              void* d_out, int out_size, void* d_ws, size_t ws_size,
                              hipStream_t stream) {
  const float* S = (const float*)d_in[0];  // Struct (8192 x 512) fp32
  const float* L = (const float*)d_in[1];  // Label  (8192)       fp32
  float* out = (float*)d_out;

  char* ws = (char*)d_ws;
  int*   sortedIdx = (int*)  (ws + OFF_SIDX);
  float* sortedLab = (float*)(ws + OFF_SLAB);
  u64*   keys0     = (u64*)  (ws + OFF_K0);
  u64*   keys1     = (u64*)  (ws + OFF_K1);
  int*   nidx      = (int*)  (ws + OFF_NIDX);
  float* wgt       = (float*)(ws + OFF_WGT);
  float* partials  = (float*)(ws + OFF_PART);

  sort_chunks_kernel<<<8, 512, 0, stream>>>(L, keys0);
  merge_pass_kernel<1024, false><<<32, 256, 0, stream>>>(keys0, keys1, nullptr, nullptr);
  merge_pass_kernel<2048, false><<<32, 256, 0, stream>>>(keys1, keys0, nullptr, nullptr);
  merge_pass_kernel<4096, true ><<<32, 256, 0, stream>>>(keys0, nullptr, sortedIdx, sortedLab);
  select_topk_kernel<<<32, 256, 0, stream>>>(sortedIdx, sortedLab, nidx, wgt);
  wmean_cos_kernel  <<<2048, 256, 0, stream>>>(S, sortedIdx, nidx, wgt, partials);
  finalize_kernel   <<<1, 256, 0, stream>>>(partials, out);
}